// Round 5
// baseline (207.802 us; speedup 1.0000x reference)
//
#include <hip/hip_runtime.h>

// Problem constants (from reference)
#define NUM_DAYS    4096
#define NUM_ATTR    512
#define MB_WIN      128
#define HID         500
#define NUM_BATCHES (NUM_DAYS - MB_WIN)        // 3968
#define NUM_Y       (NUM_BATCHES + MB_WIN - 1) // 4095 distinct day indices
#define N_PROD      (NUM_ATTR + 1)             // 513 producer blocks (v + c)
#define N_BLOCKS    4096                       // 1 wave each; all co-resident

// ---------------------------------------------------------------------------
// Single ordinary kernel (graph-capture safe), flag-based handoff:
//  * blocks 0..511: v[b] = W1[b,:].W2 ; block 512: c = b1.W2 + b2
//    each release-stores flags[b]=1 (flags start as 0xAA poison != 1,
//    so no zero-init node is needed).
//  * every block prefetches its x row into registers, then spins on the 513
//    flags (lane-strided relaxed atomic loads, L2 traffic only), fences,
//    computes y_d = x[d,:].v + c (butterfly -> all lanes), and value-scatters
//    out[(d-m)*128+m] for m = lane, lane+64.
//  * day permutation d=(b&255)*16+(b>>8): the 16 writers of any 64B output
//    line (days d0..d0+15) share b mod 8 -> same XCD -> lines merge in L2.
// Deadlock-safe: producers never wait; 4096 one-wave blocks (<64 VGPR, 0 LDS)
// all fit co-resident (16 waves/CU of 32).
// ---------------------------------------------------------------------------
__global__ __launch_bounds__(64) void k_all(
    const float* __restrict__ x,  const float* __restrict__ W1,
    const float* __restrict__ b1, const float* __restrict__ W2,
    const float* __restrict__ b2, float* __restrict__ out,
    float* __restrict__ ws) {
    float*         v     = ws;                       // 512 floats
    float*         c     = ws + 512;                 // 1 float
    unsigned int*  flags = (unsigned int*)(ws + 1024); // 513 uints

    const int b    = blockIdx.x;
    const int lane = threadIdx.x;                    // 0..63
    const int d    = ((b & 255) << 4) | (b >> 8);    // XCD-swizzled day

    // ---- prefetch this block's x row (hidden behind the fold/spin) ----
    float4 a0, a1;
    const bool has_day = (d < NUM_Y);
    if (has_day) {
        const float4* xr = (const float4*)(x + (size_t)d * NUM_ATTR);
        a0 = xr[lane];
        a1 = xr[lane + 64];
    }

    // ---- producer phase: fold weights ----
    if (b < N_PROD) {
        float acc = 0.f;
        if (b < NUM_ATTR) {
            const float* row = W1 + (size_t)b * HID;
            for (int h = lane; h < HID; h += 64) acc += row[h] * W2[h];
        } else {
            for (int h = lane; h < HID; h += 64) acc += b1[h] * W2[h];
        }
        #pragma unroll
        for (int off = 32; off >= 1; off >>= 1) acc += __shfl_down(acc, off, 64);
        if (lane == 0) {
            if (b < NUM_ATTR) v[b] = acc;
            else              *c   = acc + b2[0];
            __threadfence();  // make v/c visible before the flag
            __hip_atomic_store(&flags[b], 1u, __ATOMIC_RELEASE,
                               __HIP_MEMORY_SCOPE_AGENT);
        }
    }

    // ---- spin until all 513 producer flags are set ----
    for (;;) {
        bool ok = true;
        for (int j = lane; j < N_PROD; j += 64)
            ok &= (__hip_atomic_load(&flags[j], __ATOMIC_RELAXED,
                                     __HIP_MEMORY_SCOPE_AGENT) == 1u);
        if (__all(ok)) break;
        __builtin_amdgcn_s_sleep(2);
    }
    __threadfence();  // acquire: v/c reads below must see producer writes

    if (!has_day) return;

    // ---- day dot: y = x[d,:].v + c, broadcast to all lanes ----
    const float4* vr = (const float4*)v;
    float4 v0 = vr[lane];
    float4 v1 = vr[lane + 64];
    float acc = a0.x * v0.x + a0.y * v0.y + a0.z * v0.z + a0.w * v0.w
              + a1.x * v1.x + a1.y * v1.y + a1.z * v1.z + a1.w * v1.w;
    #pragma unroll
    for (int off = 32; off >= 1; off >>= 1) acc += __shfl_xor(acc, off, 64);
    const float yv = acc + *c;

    // ---- value-scatter: every output referencing day d, written once ----
    const int m0 = lane,      w0 = d - m0;
    const int m1 = lane + 64, w1 = d - m1;
    if (w0 >= 0 && w0 < NUM_BATCHES) out[(size_t)w0 * MB_WIN + m0] = yv;
    if (w1 >= 0 && w1 < NUM_BATCHES) out[(size_t)w1 * MB_WIN + m1] = yv;
}

extern "C" void kernel_launch(void* const* d_in, const int* in_sizes, int n_in,
                              void* d_out, int out_size, void* d_ws, size_t ws_size,
                              hipStream_t stream) {
    const float* x  = (const float*)d_in[0];  // [4096, 512]
    const float* W1 = (const float*)d_in[1];  // [512, 500]
    const float* b1 = (const float*)d_in[2];  // [500]
    const float* W2 = (const float*)d_in[3];  // [500, 1]
    const float* b2 = (const float*)d_in[4];  // [1]
    float* out = (float*)d_out;               // [507904]
    float* ws  = (float*)d_ws;

    k_all<<<N_BLOCKS, 64, 0, stream>>>(x, W1, b1, W2, b2, out, ws);
}

// Round 6
// 69.510 us; speedup vs baseline: 2.9895x; 2.9895x over previous
//
#include <hip/hip_runtime.h>

// Problem constants (from reference)
#define NUM_DAYS    4096
#define NUM_ATTR    512
#define MB_WIN      128
#define HID         500
#define NUM_BATCHES (NUM_DAYS - MB_WIN)        // 3968
#define NUM_Y       (NUM_BATCHES + MB_WIN - 1) // 4095 distinct day indices
#define OUT_ELEMS   (NUM_BATCHES * MB_WIN)     // 507904

// ---------------------------------------------------------------------------
// Kernel 1: fold the MLP:  v[a] = sum_h W1[a,h]*W2[h],  c = b1.W2 + b2
// One wave per output; float4 lane-strided row reads (125 float4 per row,
// lanes 0..60 take 2, 61..63 take 1) + scalar tail handled by bounds check.
// ---------------------------------------------------------------------------
__global__ __launch_bounds__(64) void k_fold_weights(
    const float* __restrict__ W1, const float* __restrict__ b1,
    const float* __restrict__ W2, const float* __restrict__ b2,
    float* __restrict__ v, float* __restrict__ c) {
    const int b    = blockIdx.x;
    const int lane = threadIdx.x;  // 0..63
    const float* src = (b < NUM_ATTR) ? (W1 + (size_t)b * HID) : b1;
    float acc = 0.f;
    // HID = 500 = 125 float4
    const float4* s4 = (const float4*)src;
    const float4* w4 = (const float4*)W2;
    #pragma unroll
    for (int j = lane; j < 125; j += 64) {
        float4 a = s4[j], w = w4[j];
        acc += a.x * w.x + a.y * w.y + a.z * w.z + a.w * w.w;
    }
    #pragma unroll
    for (int off = 32; off >= 1; off >>= 1) acc += __shfl_down(acc, off, 64);
    if (lane == 0) {
        if (b < NUM_ATTR) v[b] = acc;
        else              *c   = acc + b2[0];
    }
}

// ---------------------------------------------------------------------------
// Kernel 2 (fused dot + value-scatter): one wave per day d (XCD-swizzled).
//   y = x[d,:].v + c   (coalesced float4 loads, butterfly reduce -> all lanes)
//   store y to every output referencing day d:
//     out[w*128 + m], w = d - m, m in {lane, lane+64}, 0 <= w < 3968.
// Swizzle d = (b&15)*256 + (b>>4): the 16 writers (days 16g..16g+15) of any
// 64B out-line map to blocks o*16+... sharing b mod 8 -> same XCD under
// round-robin dispatch -> partial-line writes merge in one L2.
// ---------------------------------------------------------------------------
__global__ __launch_bounds__(64) void k_dot_scatter(
    const float* __restrict__ x, const float* __restrict__ v,
    const float* __restrict__ c, float* __restrict__ out) {
    const int b    = blockIdx.x;   // 0..4095
    const int lane = threadIdx.x;  // 0..63
    const int d    = ((b & 15) << 8) | (b >> 4);  // swizzled day, 0..4095
    if (d >= NUM_Y) return;

    const float4* xr = (const float4*)(x + (size_t)d * NUM_ATTR);
    const float4* vr = (const float4*)v;
    float4 a0 = xr[lane];
    float4 a1 = xr[lane + 64];
    float4 v0 = vr[lane];
    float4 v1 = vr[lane + 64];
    float acc = a0.x * v0.x + a0.y * v0.y + a0.z * v0.z + a0.w * v0.w
              + a1.x * v1.x + a1.y * v1.y + a1.z * v1.z + a1.w * v1.w;
    #pragma unroll
    for (int off = 32; off >= 1; off >>= 1) acc += __shfl_xor(acc, off, 64);
    const float yv = acc + *c;

    const int m0 = lane,      w0 = d - m0;
    const int m1 = lane + 64, w1 = d - m1;
    if (w0 >= 0 && w0 < NUM_BATCHES) out[(size_t)w0 * MB_WIN + m0] = yv;
    if (w1 >= 0 && w1 < NUM_BATCHES) out[(size_t)w1 * MB_WIN + m1] = yv;
}

extern "C" void kernel_launch(void* const* d_in, const int* in_sizes, int n_in,
                              void* d_out, int out_size, void* d_ws, size_t ws_size,
                              hipStream_t stream) {
    const float* x  = (const float*)d_in[0];  // [4096, 512]
    const float* W1 = (const float*)d_in[1];  // [512, 500]
    const float* b1 = (const float*)d_in[2];  // [500]
    const float* W2 = (const float*)d_in[3];  // [500, 1]
    const float* b2 = (const float*)d_in[4];  // [1]
    float* out = (float*)d_out;               // [507904]

    float* ws = (float*)d_ws;
    float* v  = ws;          // 512 floats
    float* c  = ws + 512;    // 1 float

    k_fold_weights<<<NUM_ATTR + 1, 64, 0, stream>>>(W1, b1, W2, b2, v, c);
    k_dot_scatter<<<NUM_DAYS, 64, 0, stream>>>(x, v, c, out);
}